// Round 10
// baseline (311.074 us; speedup 1.0000x reference)
//
#include <hip/hip_runtime.h>
#include <hip/hip_bf16.h>

using bf16 = __hip_bfloat16;
typedef __bf16 bf16x4v __attribute__((ext_vector_type(4)));
typedef __bf16 bf16x8 __attribute__((ext_vector_type(8)));
typedef float f32x4 __attribute__((ext_vector_type(4)));

#define MT 32            // tokens per block
#define SX 136           // xs row stride: 128 + 8 pad
#define SH 264           // hs row stride: 256 + 8
#define SJ 20            // NTF j-stride: 17 joints + 3 zero pad (40 B rows)
#define TFS 640          // NTF token stride = 32 * SJ
#define NTF_ELEMS 20480  // 32 tokens * 32 feats * SJ
#define MS_BASE 20496    // NTF + 16-elem zeroed tail
#define SMS 36           // Ms row stride (72 B)
#define MSW 1224         // per-wave pair-Ms: [34][36]
#define S_ELEMS 30800    // 20496 + 8*1224 + 512 read-tail = 61600 B
// GAT1 IS FOLDED INTO GEMM2 (prep-time algebra): pre1 = h @ W2g + bb1 where
//   W2g[k][i*32+f'] = sum_f (sum_j A1[i][j] * W2[k][j*32+f]) * Wg1[f][f']
//   bb1[i*32+f']    = sum_f (sum_j A1[i][j] * b2[j*32+f])    * Wg1[f][f'] + bg1[f']
// GEMM2 runs nodes & pre1 as a dual GEMM on shared A-fragments and writes
// NTF = gelu(pre1) + nodes in ONE fp32-register epilogue (no Ms, no RMW for layer 1).
// Only GAT2 remains in the wave-local section (round-9 proven body).
// launch_bounds (512,4) PERMANENT (rounds 6+8: (512,6) forces spill traffic).
// LDS plan: xs/hs (GEMM1, dead after capture) | NTF[t][f][j] overlaying | pair-Ms per wave.
// Wg m-tile 2 overreads into neighbor regions: garbage-safe (row-confined MFMA, masked stores).

__device__ __forceinline__ float bf2f(bf16 v) { return __bfloat162float(v); }

__device__ __forceinline__ float gelu_f(float x) {
    // tanh-approx GELU, branchless 9-op form (2*log2e folded into poly).
    float z  = x * fmaf(0.10294343f * x, x, 2.3022082f);
    float t  = fmaf(-2.0f, __builtin_amdgcn_rcpf(exp2f(z) + 1.0f), 1.0f);
    float hx = 0.5f * x;
    return fmaf(hx, t, hx);
}

__device__ __forceinline__ bf16x8 ld8(const bf16* p) {       // 16B-aligned
    return *reinterpret_cast<const bf16x8*>(p);
}
__device__ __forceinline__ bf16x8 ld8u(const bf16* p) {      // 8B-aligned (two b64)
    bf16x4v lo = *reinterpret_cast<const bf16x4v*>(p);
    bf16x4v hi = *reinterpret_cast<const bf16x4v*>(p + 4);
    return __builtin_shufflevector(lo, hi, 0, 1, 2, 3, 4, 5, 6, 7);
}
__device__ __forceinline__ f32x4 mfma16(bf16x8 a, bf16x8 b, f32x4 c) {
    return __builtin_amdgcn_mfma_f32_16x16x32_bf16(a, b, c, 0, 0, 0);
}

// ---------------- megaprep: ONE kernel for all prep ----------------
// Per block: softmax A1,A2 into LDS. Then by global idx range (all writes coalesced):
//  [0,32768)        w1t[n*128+k]  = bf16(W1[k*256+n])
//  [32768,172032)   w2t[n*256+k]  = bf16(W2[k*544+n])
//  [172032,311296)  w2g[n'*256+k] = bf16(fold above)            (544 fma/thread)
//  [311296,312320)  wg2t[f'*32+f] = bf16(Wg2[f*32+f'])
//  [312320,313344)  mb2 fragment table (zero-padded A2, B-layout)
//  [313344,313888)  bb1[n'] fp32
__global__ void megaprep(const float* __restrict__ W1, const float* __restrict__ W2,
                         const float* __restrict__ Wg1, const float* __restrict__ Wg2,
                         const float* __restrict__ adj1, const float* __restrict__ adj2,
                         const float* __restrict__ b2, const float* __restrict__ bg1,
                         bf16* __restrict__ w1t, bf16* __restrict__ w2t,
                         bf16* __restrict__ w2g, bf16* __restrict__ wg2t,
                         bf16* __restrict__ mb2, float* __restrict__ bb1) {
    __shared__ float A1s[289], A2s[289];
    {
        int t = threadIdx.x;
        if (t < 17 || (t >= 32 && t < 49)) {
            const float* adj = (t < 17) ? adj1 : adj2;
            float*       A   = (t < 17) ? A1s  : A2s;
            int row = (t < 17) ? t : (t - 32);
            float v[17]; float mx = -1e30f;
            for (int j = 0; j < 17; ++j) { v[j] = adj[row * 17 + j]; mx = fmaxf(mx, v[j]); }
            float s = 0.0f;
            for (int j = 0; j < 17; ++j) { v[j] = __expf(v[j] - mx); s += v[j]; }
            float inv = 1.0f / s;
            for (int j = 0; j < 17; ++j) A[row * 17 + j] = v[j] * inv;
        }
    }
    __syncthreads();

    int idx = blockIdx.x * 256 + threadIdx.x;
    if (idx < 32768) {
        int n = idx >> 7, k = idx & 127;
        w1t[idx] = __float2bfloat16(W1[k * 256 + n]);
    } else if (idx < 172032) {
        int o = idx - 32768;
        int n = o >> 8, k = o & 255;
        w2t[o] = __float2bfloat16(W2[k * 544 + n]);
    } else if (idx < 311296) {
        int o = idx - 172032;
        int np = o >> 8, k = o & 255;          // n' = i*32+f', k
        int i = np >> 5, fp = np & 31;
        const float* wrow = W2 + k * 544;
        float acc = 0.0f;
        for (int j = 0; j < 17; ++j) {
            float aj = A1s[i * 17 + j];
            float t = 0.0f;
            for (int f = 0; f < 32; ++f)
                t = fmaf(Wg1[f * 32 + fp], wrow[j * 32 + f], t);
            acc = fmaf(aj, t, acc);
        }
        w2g[o] = __float2bfloat16(acc);
    } else if (idx < 312320) {
        int o = idx - 311296;
        int fp = o >> 5, f = o & 31;
        wg2t[o] = __float2bfloat16(Wg2[f * 32 + fp]);
    } else if (idx < 313344) {
        int o = idx - 312320;
        int nt = o >> 9, lane = (o >> 3) & 63, e = o & 7;
        int i = nt * 16 + (lane & 15);
        int j = (lane >> 4) * 8 + e;
        float v = (i < 17 && j < 17) ? A2s[i * 17 + j] : 0.0f;
        mb2[o] = __float2bfloat16(v);
    } else if (idx < 313888) {
        int np = idx - 313344;
        int i = np >> 5, fp = np & 31;
        float acc = bg1[fp];
        for (int j = 0; j < 17; ++j) {
            float aj = A1s[i * 17 + j];
            float t = 0.0f;
            for (int f = 0; f < 32; ++f)
                t = fmaf(Wg1[f * 32 + fp], b2[j * 32 + f], t);
            acc = fmaf(aj, t, acc);
        }
        bb1[np] = acc;
    }
}

// ---------------- main fused kernel ----------------
__global__ __launch_bounds__(512, 4)
void gat_main(const float* __restrict__ x,
              const float* __restrict__ b1, const float* __restrict__ b2,
              const float* __restrict__ bg2, const float* __restrict__ bb1,
              const bf16* __restrict__ w1t, const bf16* __restrict__ w2t,
              const bf16* __restrict__ w2g, const bf16* __restrict__ wg2t,
              const bf16* __restrict__ mb2,
              const float* __restrict__ Wc, const float* __restrict__ bc,
              float* __restrict__ out) {
    __shared__ alignas(16) bf16 S[S_ELEMS];
    bf16* xs = S;            // [32][SX]
    bf16* hs = S + 4352;     // [32][SH]

    const int tid  = threadIdx.x;
    const int w    = tid >> 6;      // 0..7
    const int lane = tid & 63;
    const int l    = lane & 15;
    const int q    = lane >> 4;
    const int t0   = blockIdx.x * MT;

    // ---- stage x tile (fp32 -> bf16) ----
    for (int c = tid; c < 1024; c += 512) {
        int row = c >> 5, c4 = c & 31;
        const float4 v = *reinterpret_cast<const float4*>(x + (size_t)(t0 + row) * 128 + c4 * 4);
        bf16 tmp[4] = { __float2bfloat16(v.x), __float2bfloat16(v.y),
                        __float2bfloat16(v.z), __float2bfloat16(v.w) };
        *reinterpret_cast<ushort4*>(xs + row * SX + c4 * 4) =
            *reinterpret_cast<const ushort4*>(tmp);
    }
    __syncthreads();

    // ---- GEMM1: h = gelu(x @ W1 + b1)  [32,128]@[128,256], 2 n-tiles/wave ----
    for (int nt = w * 2; nt < w * 2 + 2; ++nt) {
        int n = nt * 16 + l;
        bf16x8 bfr[4];
        const bf16* wp = w1t + n * 128 + q * 8;
#pragma unroll
        for (int kf = 0; kf < 4; ++kf) bfr[kf] = ld8(wp + kf * 32);
        float bias = b1[n];
#pragma unroll
        for (int mt = 0; mt < 2; ++mt) {
            f32x4 acc = {0.f, 0.f, 0.f, 0.f};
            const bf16* ap = xs + (mt * 16 + l) * SX + q * 8;
#pragma unroll
            for (int kf = 0; kf < 4; ++kf)
                acc = mfma16(ld8(ap + kf * 32), bfr[kf], acc);
            int trow = mt * 16 + q * 4;
#pragma unroll
            for (int r = 0; r < 4; ++r)
                hs[(trow + r) * SH + n] = __float2bfloat16(gelu_f(acc[r] + bias));
        }
    }
    __syncthreads();

    // ---- DUAL GEMM2: nodes = h@W2+b2, pre1 = h@W2g+bb1; NTF = gelu(pre1)+nodes ----
    {
        bf16x8 af[2][8];    // register-capture all of this thread's hs fragments
#pragma unroll
        for (int mt = 0; mt < 2; ++mt)
#pragma unroll
            for (int kf = 0; kf < 8; ++kf)
                af[mt][kf] = ld8(hs + (mt * 16 + l) * SH + kf * 32 + q * 8);
        __syncthreads();     // hs fully captured before NTF (overlaying) is written

        // zero NTF pad: j=17..19 of every (t,f) row + 16-elem tail (div-free form)
        for (int rowz = tid; rowz < 1024; rowz += 512) {
            int base = rowz * SJ + 17;
            S[base]     = __float2bfloat16(0.f);
            S[base + 1] = __float2bfloat16(0.f);
            S[base + 2] = __float2bfloat16(0.f);
        }
        if (tid < 16) S[NTF_ELEMS + tid] = __float2bfloat16(0.f);

        for (int nt = w; nt < 34; nt += 8) {
            int n = nt * 16 + l;
            float bias2 = b2[n];
            float biasP = bb1[n];
            int i = n >> 5, f = n & 31;
            f32x4 a0 = {0.f, 0.f, 0.f, 0.f}, a1 = {0.f, 0.f, 0.f, 0.f};
            f32x4 c0 = {0.f, 0.f, 0.f, 0.f}, c1 = {0.f, 0.f, 0.f, 0.f};
            const bf16* wp = w2t + n * 256 + q * 8;
            const bf16* gp = w2g + n * 256 + q * 8;
#pragma unroll
            for (int kf = 0; kf < 8; ++kf) {
                bf16x8 bfr = ld8(wp + kf * 32);
                a0 = mfma16(af[0][kf], bfr, a0);
                a1 = mfma16(af[1][kf], bfr, a1);
                bf16x8 gfr = ld8(gp + kf * 32);
                c0 = mfma16(af[0][kf], gfr, c0);
                c1 = mfma16(af[1][kf], gfr, c1);
            }
#pragma unroll
            for (int mt = 0; mt < 2; ++mt) {
                const f32x4 accN = mt ? a1 : a0;
                const f32x4 accP = mt ? c1 : c0;
#pragma unroll
                for (int r = 0; r < 4; ++r) {
                    int t = mt * 16 + q * 4 + r;
                    float nodesv = accN[r] + bias2;
                    float v = gelu_f(accP[r] + biasP) + nodesv;   // GAT1 done here
                    S[t * TFS + f * SJ + i] = __float2bfloat16(v);
                }
            }
        }
    }
    __syncthreads();
    // ======== from here on, everything is WAVE-LOCAL: no more barriers ========

    bf16* ms_p = S + MS_BASE + w * MSW;    // this wave's [34][36] pair-Ms scratch

    // ---- GAT2 (only remaining graph layer): mix + Wg + gelu + residual ----
    {
        bf16x8 mixB[2] = { ld8(mb2 + lane * 8), ld8(mb2 + 512 + lane * 8) };
        bf16x8 wfr[2];
#pragma unroll
        for (int nt = 0; nt < 2; ++nt) wfr[nt] = ld8(wg2t + (nt * 16 + l) * 32 + q * 8);
        float bgf[2] = { bg2[l], bg2[16 + l] };

        // two 2-token pairs per wave (wave owns tokens w*4 .. w*4+3)
        for (int p = 0; p < 2; ++p) {
            const int T0 = w * 4 + p * 2;

            // ---- mix GEMM for both tokens of the pair -> pair-Ms (i-major) ----
#pragma unroll
            for (int u = 0; u < 4; ++u) {              // u = tl*2 + ft
                int tl = u >> 1, ft = u & 1;
                int R = (T0 + tl) * 32 + ft * 16 + l;  // NTF row (t*32+f)
                bf16x8 afr = ld8u(S + R * SJ + q * 8); // pad/overread killed by mixB zeros
                int f0 = ft * 16 + q * 4;              // 4 consecutive f (D-rows)
#pragma unroll
                for (int nt = 0; nt < 2; ++nt) {
                    f32x4 acc = {0.f, 0.f, 0.f, 0.f};
                    acc = mfma16(afr, mixB[nt], acc);
                    union { ushort4 u4; bf16 b[4]; } pk;
#pragma unroll
                    for (int r = 0; r < 4; ++r) pk.b[r] = __float2bfloat16(acc[r]);
                    if (nt == 0) {                     // i = l in 0..15: always valid
                        *reinterpret_cast<ushort4*>(ms_p + (tl * 16 + l) * SMS + f0) = pk.u4;
                    } else if (l == 0) {               // i = 16: row 32+tl
                        *reinterpret_cast<ushort4*>(ms_p + (32 + tl) * SMS + f0) = pk.u4;
                    }
                }
            }

            // ---- Wg GEMM + gelu + residual: 3 m-tiles finish BOTH tokens ----
#pragma unroll
            for (int mt = 0; mt < 3; ++mt) {
                bf16x8 afr = ld8u(ms_p + (mt * 16 + l) * SMS + q * 8);
#pragma unroll
                for (int nt = 0; nt < 2; ++nt) {
                    f32x4 acc = {0.f, 0.f, 0.f, 0.f};
                    acc = mfma16(afr, wfr[nt], acc);
                    int fp = nt * 16 + l;
                    if (mt < 2) {
                        int i0 = q * 4;                // 0,4,8,12 (always < 16)
                        bf16* ptr = S + (T0 + mt) * TFS + fp * SJ + i0;
                        union { ushort4 u4; bf16 b[4]; } old, nw;
                        old.u4 = *reinterpret_cast<const ushort4*>(ptr);
#pragma unroll
                        for (int r = 0; r < 4; ++r) {
                            float v = gelu_f(acc[r] + bgf[nt]) + bf2f(old.b[r]);
                            nw.b[r] = __float2bfloat16(v);
                        }
                        *reinterpret_cast<ushort4*>(ptr) = nw.u4;
                    } else if (q == 0) {
#pragma unroll
                        for (int r = 0; r < 2; ++r) {  // r=0 -> T0 i=16, r=1 -> T0+1 i=16
                            bf16* pp = S + (T0 + r) * TFS + fp * SJ + 16;
                            float v = gelu_f(acc[r] + bgf[nt]) + bf2f(*pp);
                            *pp = __float2bfloat16(v);
                        }
                    }
                }
            }
        }
    }

    // ---- coord projection (wave-local): out = g2 @ Wc + bc (fp32 output) ----
    for (int s = lane; s < 68; s += 64) {
        int tl = s / 17, i = s - tl * 17;
        int t  = w * 4 + tl;
        const bf16* gp = S + t * TFS + i;
        float o0 = bc[0], o1 = bc[1];
#pragma unroll
        for (int f = 0; f < 32; ++f) {
            float v = bf2f(gp[f * SJ]);
            o0 = fmaf(v, Wc[f * 2 + 0], o0);
            o1 = fmaf(v, Wc[f * 2 + 1], o1);
        }
        float2 pr = { o0, o1 };
        reinterpret_cast<float2*>(out)[(size_t)(t0 + t) * 17 + i] = pr;
    }
}

extern "C" void kernel_launch(void* const* d_in, const int* in_sizes, int n_in,
                              void* d_out, int out_size, void* d_ws, size_t ws_size,
                              hipStream_t stream) {
    const float* x    = (const float*)d_in[0];
    const float* W1   = (const float*)d_in[1];
    const float* b1   = (const float*)d_in[2];
    const float* W2   = (const float*)d_in[3];
    const float* b2   = (const float*)d_in[4];
    const float* adj1 = (const float*)d_in[5];
    const float* Wg1  = (const float*)d_in[6];
    const float* bg1  = (const float*)d_in[7];
    const float* adj2 = (const float*)d_in[8];
    const float* Wg2  = (const float*)d_in[9];
    const float* bg2  = (const float*)d_in[10];
    const float* Wc   = (const float*)d_in[11];
    const float* bc   = (const float*)d_in[12];

    char* ws = (char*)d_ws;
    bf16*  w1t  = (bf16*)(ws + 0);        // 65536 B
    bf16*  w2t  = (bf16*)(ws + 65536);    // 278528 B -> 344064
    bf16*  w2g  = (bf16*)(ws + 344064);   // 278528 B -> 622592
    bf16*  wg2t = (bf16*)(ws + 622592);   // 2048 B   -> 624640
    bf16*  mb2  = (bf16*)(ws + 624640);   // 2048 B   -> 626688
    float* bb1  = (float*)(ws + 626688);  // 2176 B   -> 628864

    megaprep<<<1227, 256, 0, stream>>>(W1, W2, Wg1, Wg2, adj1, adj2, b2, bg1,
                                       w1t, w2t, w2g, wg2t, mb2, bb1);

    const int tokens = 16 * 4096;
    gat_main<<<tokens / MT, 512, 0, stream>>>(x, b1, b2, bg2, bb1,
                                              w1t, w2t, w2g, wg2t, mb2,
                                              Wc, bc, (float*)d_out);
}

// Round 11
// 215.992 us; speedup vs baseline: 1.4402x; 1.4402x over previous
//
#include <hip/hip_runtime.h>
#include <hip/hip_bf16.h>

using bf16 = __hip_bfloat16;
typedef __bf16 bf16x4v __attribute__((ext_vector_type(4)));
typedef __bf16 bf16x8 __attribute__((ext_vector_type(8)));
typedef float f32x4 __attribute__((ext_vector_type(4)));

#define MT 32            // tokens per block
#define SX 136           // xs row stride: 128 + 8 pad
#define SH 264           // hs row stride: 256 + 8
#define SJ 20            // NTF j-stride: 17 joints + 3 zero pad (40 B rows)
#define TFS 640          // NTF token stride = 32 * SJ
#define NTF_ELEMS 20480  // 32 tokens * 32 feats * SJ
#define MS_BASE 20496    // NTF + 16-elem zeroed tail
#define SMS 36           // Ms row stride (72 B)
#define MSW 1224         // per-wave pair-Ms: [34][36]
#define S_ELEMS 30800    // 20496 + 8*1224 + 512 read-tail = 61600 B
// ROUND 11 = round-9 body (best verified: 138.5 us) + two changes:
//  (a) LDS-read HOISTING in the GAT section: preload all 8 NTF A-fragments per
//      layer and the 3 Wg A-fragments per pair into registers BEFORE any
//      aliasing ds_write. Theory: compiler can't prove ds_read/ds_write
//      disjointness on runtime offsets into S[], so it serializes phases with
//      lgkmcnt waits; hoisting breaks the false dependency (the ~56 us stall).
//  (b) prep_mixb merged into prep_kernel (block 0: softmax in LDS -> mb tables).
// GAT1-fold (round 10) REVERTED: it added ~68 MFMA/wave + doubled the GEMM2
// weight stream to remove a 28-MFMA layer -- net regression.
// launch_bounds (512,4) PERMANENT (rounds 6+8: (512,6) budget forces spills).
// LDS plan: xs/hs (GEMM1, dead after capture) | NTF[t][f][j] overlay | pair-Ms/wave.
// Wg m-tile 2 overreads neighbor regions: garbage-safe (row-confined MFMA, masked).

__device__ __forceinline__ float bf2f(bf16 v) { return __bfloat162float(v); }

__device__ __forceinline__ float gelu_f(float x) {
    // tanh-approx GELU, branchless 9-op form (2*log2e folded into poly).
    float z  = x * fmaf(0.10294343f * x, x, 2.3022082f);
    float t  = fmaf(-2.0f, __builtin_amdgcn_rcpf(exp2f(z) + 1.0f), 1.0f);
    float hx = 0.5f * x;
    return fmaf(hx, t, hx);
}

__device__ __forceinline__ bf16x8 ld8(const bf16* p) {       // 16B-aligned
    return *reinterpret_cast<const bf16x8*>(p);
}
__device__ __forceinline__ bf16x8 ld8u(const bf16* p) {      // 8B-aligned (two b64)
    bf16x4v lo = *reinterpret_cast<const bf16x4v*>(p);
    bf16x4v hi = *reinterpret_cast<const bf16x4v*>(p + 4);
    return __builtin_shufflevector(lo, hi, 0, 1, 2, 3, 4, 5, 6, 7);
}
__device__ __forceinline__ f32x4 mfma16(bf16x8 a, bf16x8 b, f32x4 c) {
    return __builtin_amdgcn_mfma_f32_16x16x32_bf16(a, b, c, 0, 0, 0);
}

// ---------------- prep (single kernel): transposes + softmax + mixB tables ----------------
__global__ void prep_kernel(const float* __restrict__ W1, const float* __restrict__ W2,
                            const float* __restrict__ Wg1, const float* __restrict__ Wg2,
                            const float* __restrict__ adj1, const float* __restrict__ adj2,
                            bf16* __restrict__ w1t, bf16* __restrict__ w2t,
                            bf16* __restrict__ wg1t, bf16* __restrict__ wg2t,
                            bf16* __restrict__ mb) {
    if (blockIdx.x == 0) {
        __shared__ float A1s[289], A2s[289];
        int t = threadIdx.x;
        if (t < 17 || (t >= 32 && t < 49)) {
            const float* adj = (t < 17) ? adj1 : adj2;
            float*       A   = (t < 17) ? A1s  : A2s;
            int row = (t < 17) ? t : (t - 32);
            float v[17]; float mx = -1e30f;
            for (int j = 0; j < 17; ++j) { v[j] = adj[row * 17 + j]; mx = fmaxf(mx, v[j]); }
            float s = 0.0f;
            for (int j = 0; j < 17; ++j) { v[j] = __expf(v[j] - mx); s += v[j]; }
            float inv = 1.0f / s;
            for (int j = 0; j < 17; ++j) A[row * 17 + j] = v[j] * inv;
        }
        __syncthreads();
        // mixB fragment tables, both layers: B[k=j][col=i] = A_soft[i][j], zero-padded
        for (int o = threadIdx.x; o < 2048; o += 256) {
            int g = o >> 10, rem = o & 1023;
            int nt = rem >> 9, lane = (rem >> 3) & 63, e = rem & 7;
            int i = nt * 16 + (lane & 15);
            int j = (lane >> 4) * 8 + e;
            const float* A = g ? A2s : A1s;
            float v = (i < 17 && j < 17) ? A[i * 17 + j] : 0.0f;
            mb[o] = __float2bfloat16(v);
        }
    }
    int idx = blockIdx.x * 256 + threadIdx.x;
    if (idx < 32768) {                       // W1: r=k(128), c=n(256)
        int r = idx >> 8, c = idx & 255;
        w1t[c * 128 + r] = __float2bfloat16(W1[idx]);
    } else if (idx < 172032) {               // W2: r=k(256), c=n(544)
        int j = idx - 32768;
        int r = j / 544, c = j % 544;
        w2t[c * 256 + r] = __float2bfloat16(W2[j]);
    } else if (idx < 173056) {               // Wg1 -> wg1t[f'][f]
        int j = idx - 172032;
        wg1t[(j & 31) * 32 + (j >> 5)] = __float2bfloat16(Wg1[j]);
    } else if (idx < 174080) {
        int j = idx - 173056;
        wg2t[(j & 31) * 32 + (j >> 5)] = __float2bfloat16(Wg2[j]);
    }
}

// ---------------- main fused kernel ----------------
__global__ __launch_bounds__(512, 4)
void gat_main(const float* __restrict__ x,
              const float* __restrict__ b1, const float* __restrict__ b2,
              const float* __restrict__ bg1, const float* __restrict__ bg2,
              const bf16* __restrict__ w1t, const bf16* __restrict__ w2t,
              const bf16* __restrict__ wg1t, const bf16* __restrict__ wg2t,
              const bf16* __restrict__ mb,
              const float* __restrict__ Wc, const float* __restrict__ bc,
              float* __restrict__ out) {
    __shared__ alignas(16) bf16 S[S_ELEMS];
    bf16* xs = S;            // [32][SX]
    bf16* hs = S + 4352;     // [32][SH]

    const int tid  = threadIdx.x;
    const int w    = tid >> 6;      // 0..7
    const int lane = tid & 63;
    const int l    = lane & 15;
    const int q    = lane >> 4;
    const int t0   = blockIdx.x * MT;

    // ---- stage x tile (fp32 -> bf16) ----
    for (int c = tid; c < 1024; c += 512) {
        int row = c >> 5, c4 = c & 31;
        const float4 v = *reinterpret_cast<const float4*>(x + (size_t)(t0 + row) * 128 + c4 * 4);
        bf16 tmp[4] = { __float2bfloat16(v.x), __float2bfloat16(v.y),
                        __float2bfloat16(v.z), __float2bfloat16(v.w) };
        *reinterpret_cast<ushort4*>(xs + row * SX + c4 * 4) =
            *reinterpret_cast<const ushort4*>(tmp);
    }
    __syncthreads();

    // ---- GEMM1: h = gelu(x @ W1 + b1)  [32,128]@[128,256], 2 n-tiles/wave ----
    for (int nt = w * 2; nt < w * 2 + 2; ++nt) {
        int n = nt * 16 + l;
        bf16x8 bfr[4];
        const bf16* wp = w1t + n * 128 + q * 8;
#pragma unroll
        for (int kf = 0; kf < 4; ++kf) bfr[kf] = ld8(wp + kf * 32);
        float bias = b1[n];
#pragma unroll
        for (int mt = 0; mt < 2; ++mt) {
            f32x4 acc = {0.f, 0.f, 0.f, 0.f};
            const bf16* ap = xs + (mt * 16 + l) * SX + q * 8;
#pragma unroll
            for (int kf = 0; kf < 4; ++kf)
                acc = mfma16(ld8(ap + kf * 32), bfr[kf], acc);
            int trow = mt * 16 + q * 4;
#pragma unroll
            for (int r = 0; r < 4; ++r)
                hs[(trow + r) * SH + n] = __float2bfloat16(gelu_f(acc[r] + bias));
        }
    }
    __syncthreads();

    // ---- GEMM2: nodes = h @ W2 + b2 -> NTF[t][f][i] scatter (overlays xs+hs) ----
    {
        bf16x8 af[2][8];    // register-capture all of this thread's hs fragments
#pragma unroll
        for (int mt = 0; mt < 2; ++mt)
#pragma unroll
            for (int kf = 0; kf < 8; ++kf)
                af[mt][kf] = ld8(hs + (mt * 16 + l) * SH + kf * 32 + q * 8);
        __syncthreads();     // hs fully captured before NTF (overlaying) is written

        // zero NTF pad: j=17..19 of every (t,f) row + 16-elem tail (div-free)
        for (int rowz = tid; rowz < 1024; rowz += 512) {
            int base = rowz * SJ + 17;
            S[base]     = __float2bfloat16(0.f);
            S[base + 1] = __float2bfloat16(0.f);
            S[base + 2] = __float2bfloat16(0.f);
        }
        if (tid < 16) S[NTF_ELEMS + tid] = __float2bfloat16(0.f);

        for (int nt = w; nt < 34; nt += 8) {
            int n = nt * 16 + l;
            float bias = b2[n];
            int i = n >> 5, f = n & 31;
            f32x4 a0 = {0.f, 0.f, 0.f, 0.f}, a1 = {0.f, 0.f, 0.f, 0.f};
            const bf16* wp = w2t + n * 256 + q * 8;
#pragma unroll
            for (int kf = 0; kf < 8; ++kf) {
                bf16x8 bfr = ld8(wp + kf * 32);
                a0 = mfma16(af[0][kf], bfr, a0);
                a1 = mfma16(af[1][kf], bfr, a1);
            }
#pragma unroll
            for (int mt = 0; mt < 2; ++mt) {
                const f32x4 acc = mt ? a1 : a0;
#pragma unroll
                for (int r = 0; r < 4; ++r) {
                    int t = mt * 16 + q * 4 + r;
                    S[t * TFS + f * SJ + i] = __float2bfloat16(acc[r] + bias);
                }
            }
        }
    }
    __syncthreads();
    // ======== from here on, everything is WAVE-LOCAL: no more barriers ========

    bf16* ms_p = S + MS_BASE + w * MSW;    // this wave's [34][36] pair-Ms scratch

    for (int g = 0; g < 2; ++g) {
        const bf16* mbg = mb + g * 1024;
        const bf16* wgt = g ? wg2t : wg1t;
        const float* bg = g ? bg2 : bg1;

        bf16x8 mixB[2] = { ld8(mbg + lane * 8), ld8(mbg + 512 + lane * 8) };
        bf16x8 wfr[2];
#pragma unroll
        for (int nt = 0; nt < 2; ++nt) wfr[nt] = ld8(wgt + (nt * 16 + l) * 32 + q * 8);
        float bgf[2] = { bg[l], bg[16 + l] };

        // HOIST: preload all 8 NTF A-fragments (4 tokens x 2 f-tiles) for this
        // layer before ANY ds_write of the layer. Pair-1's inputs are thus in
        // registers before pair-0's Wg stores -- no false ds ordering.
        bf16x8 nfr[8];
#pragma unroll
        for (int u = 0; u < 8; ++u) {
            int tl = u >> 1, ft = u & 1;               // token-in-wave, f-tile
            int R = (w * 4 + tl) * 32 + ft * 16 + l;   // NTF row (t*32+f)
            nfr[u] = ld8u(S + R * SJ + q * 8);
        }

        // two 2-token pairs per wave (wave owns tokens w*4 .. w*4+3)
        for (int p = 0; p < 2; ++p) {
            const int T0 = w * 4 + p * 2;

            // ---- mix GEMM for both tokens of the pair -> pair-Ms (i-major) ----
#pragma unroll
            for (int u = 0; u < 4; ++u) {              // u = tl_local*2 + ft
                int ft = u & 1;
                bf16x8 afr = nfr[p * 4 + u];
                int tl = u >> 1;
                int f0 = ft * 16 + q * 4;              // 4 consecutive f (D-rows)
#pragma unroll
                for (int nt = 0; nt < 2; ++nt) {
                    f32x4 acc = {0.f, 0.f, 0.f, 0.f};
                    acc = mfma16(afr, mixB[nt], acc);
                    union { ushort4 u4; bf16 b[4]; } pk;
#pragma unroll
                    for (int r = 0; r < 4; ++r) pk.b[r] = __float2bfloat16(acc[r]);
                    if (nt == 0) {                     // i = l in 0..15: always valid
                        *reinterpret_cast<ushort4*>(ms_p + (tl * 16 + l) * SMS + f0) = pk.u4;
                    } else if (l == 0) {               // i = 16: row 32+tl
                        *reinterpret_cast<ushort4*>(ms_p + (32 + tl) * SMS + f0) = pk.u4;
                    }
                }
            }

            // ---- Wg GEMM + gelu + residual: 3 m-tiles finish BOTH tokens ----
            // HOIST: all 3 A-fragment reads before any epilogue RMW store.
            bf16x8 wa[3];
#pragma unroll
            for (int mt = 0; mt < 3; ++mt)
                wa[mt] = ld8u(ms_p + (mt * 16 + l) * SMS + q * 8);
#pragma unroll
            for (int mt = 0; mt < 3; ++mt) {
#pragma unroll
                for (int nt = 0; nt < 2; ++nt) {
                    f32x4 acc = {0.f, 0.f, 0.f, 0.f};
                    acc = mfma16(wa[mt], wfr[nt], acc);
                    int fp = nt * 16 + l;
                    if (mt < 2) {
                        int i0 = q * 4;                // 0,4,8,12 (always < 16)
                        bf16* ptr = S + (T0 + mt) * TFS + fp * SJ + i0;
                        union { ushort4 u4; bf16 b[4]; } old, nw;
                        old.u4 = *reinterpret_cast<const ushort4*>(ptr);
#pragma unroll
                        for (int r = 0; r < 4; ++r) {
                            float v = gelu_f(acc[r] + bgf[nt]) + bf2f(old.b[r]);
                            nw.b[r] = __float2bfloat16(v);
                        }
                        *reinterpret_cast<ushort4*>(ptr) = nw.u4;
                    } else if (q == 0) {
#pragma unroll
                        for (int r = 0; r < 2; ++r) {  // r=0 -> T0 i=16, r=1 -> T0+1 i=16
                            bf16* pp = S + (T0 + r) * TFS + fp * SJ + 16;
                            float v = gelu_f(acc[r] + bgf[nt]) + bf2f(*pp);
                            *pp = __float2bfloat16(v);
                        }
                    }
                }
            }
        }
    }

    // ---- coord projection (wave-local): out = g2 @ Wc + bc (fp32 output) ----
    for (int s = lane; s < 68; s += 64) {
        int tl = s / 17, i = s - tl * 17;
        int t  = w * 4 + tl;
        const bf16* gp = S + t * TFS + i;
        float o0 = bc[0], o1 = bc[1];
#pragma unroll
        for (int f = 0; f < 32; ++f) {
            float v = bf2f(gp[f * SJ]);
            o0 = fmaf(v, Wc[f * 2 + 0], o0);
            o1 = fmaf(v, Wc[f * 2 + 1], o1);
        }
        float2 pr = { o0, o1 };
        reinterpret_cast<float2*>(out)[(size_t)(t0 + t) * 17 + i] = pr;
    }
}

extern "C" void kernel_launch(void* const* d_in, const int* in_sizes, int n_in,
                              void* d_out, int out_size, void* d_ws, size_t ws_size,
                              hipStream_t stream) {
    const float* x    = (const float*)d_in[0];
    const float* W1   = (const float*)d_in[1];
    const float* b1   = (const float*)d_in[2];
    const float* W2   = (const float*)d_in[3];
    const float* b2   = (const float*)d_in[4];
    const float* adj1 = (const float*)d_in[5];
    const float* Wg1  = (const float*)d_in[6];
    const float* bg1  = (const float*)d_in[7];
    const float* adj2 = (const float*)d_in[8];
    const float* Wg2  = (const float*)d_in[9];
    const float* bg2  = (const float*)d_in[10];
    const float* Wc   = (const float*)d_in[11];
    const float* bc   = (const float*)d_in[12];

    char* ws = (char*)d_ws;
    bf16*  w1t  = (bf16*)(ws + 0);        // 65536 B
    bf16*  w2t  = (bf16*)(ws + 65536);    // 278528 B -> 344064
    bf16*  wg1t = (bf16*)(ws + 344064);   // 2048 B   -> 346112
    bf16*  wg2t = (bf16*)(ws + 346112);   // 2048 B   -> 348160
    bf16*  mbt  = (bf16*)(ws + 348160);   // 4096 B   -> 352256

    prep_kernel<<<680, 256, 0, stream>>>(W1, W2, Wg1, Wg2, adj1, adj2,
                                         w1t, w2t, wg1t, wg2t, mbt);

    const int tokens = 16 * 4096;
    gat_main<<<tokens / MT, 512, 0, stream>>>(x, b1, b2, bg1, bg2,
                                              w1t, w2t, wg1t, wg2t, mbt,
                                              Wc, bc, (float*)d_out);
}